// Round 1
// baseline (547.682 us; speedup 1.0000x reference)
//
#include <hip/hip_runtime.h>
#include <float.h>
#include <stdint.h>

#define D_DIM 784
#define KPAD 832            // 13 x 64
#define N_TRAIN 50000
#define NPAD 50176          // 196 x 256
#define B_TEST 2048
#define N_CLASSES 10
#define TOPK 5
#define NBLK 196            // 50176 / 256
#define SEL 8               // exact-rescore candidate count per row
#define NT 13               // K tiles of 64

typedef __attribute__((ext_vector_type(8))) _Float16 half8;
typedef __attribute__((ext_vector_type(4))) float float4v;

__device__ inline unsigned umax32(unsigned a, unsigned b) { return a > b ? a : b; }

// monotonic float->u32 key, low 8 bits replaced by col (0..255)
__device__ inline unsigned pack_key(float s, int col) {
    unsigned u = __float_as_uint(s);
    unsigned mask = (unsigned)((int)u >> 31) | 0x80000000u;
    unsigned k = u ^ mask;
    return (k & 0xFFFFFF00u) | (unsigned)col;
}

// branchless sorted-insert (desc) of u64 into 8-deep list
__device__ inline void ins8(unsigned long long* tk, unsigned long long v) {
    #pragma unroll
    for (int s = 0; s < SEL; ++s) {
        unsigned long long mx = v > tk[s] ? v : tk[s];
        unsigned long long mn = v > tk[s] ? tk[s] : v;
        tk[s] = mx; v = mn;
    }
}

// branchless sorted-insert (desc) of u32 into 5-deep list
__device__ inline void ins5u(unsigned* tk, unsigned v) {
    #pragma unroll
    for (int s = 0; s < TOPK; ++s) {
        unsigned mx = v > tk[s] ? v : tk[s];
        unsigned mn = v > tk[s] ? tk[s] : v;
        tk[s] = mx; v = mn;
    }
}

// float pair-insert for fallback path
#define INSERT5(tvarr, tiarr, CV, CI)                                   \
    {                                                                   \
        float _cv = (CV); int _ci = (CI);                               \
        _Pragma("unroll")                                               \
        for (int _s = 0; _s < TOPK; ++_s) {                             \
            bool _bet = (_cv > tvarr[_s]) ||                            \
                        (_cv == tvarr[_s] && _ci < tiarr[_s]);          \
            float _fv = _bet ? tvarr[_s] : _cv;                         \
            int   _fi = _bet ? tiarr[_s] : _ci;                         \
            tvarr[_s] = _bet ? _cv : tvarr[_s];                         \
            tiarr[_s] = _bet ? _ci : tiarr[_s];                         \
            _cv = _fv; _ci = _fi;                                       \
        }                                                               \
    }

// ------------- fused split fp32->f16 + rowsum (one wave per row) -------------
__global__ __launch_bounds__(256)
void split_rowsum(const float* __restrict__ src, _Float16* __restrict__ hi,
                  float* __restrict__ strain, int rows_src, int rows_pad, int do_sum) {
    int row = blockIdx.x * 4 + (threadIdx.x >> 6);
    int lane = threadIdx.x & 63;
    if (row >= rows_pad) return;
    const float* p = src + (size_t)row * D_DIM;
    float sum = 0.f;

    // group 0: g = lane (0..63, all real)
    {
        float v[8];
        if (row < rows_src) {
            float4 a = *(const float4*)(p + lane * 8);
            float4 b = *(const float4*)(p + lane * 8 + 4);
            v[0]=a.x; v[1]=a.y; v[2]=a.z; v[3]=a.w; v[4]=b.x; v[5]=b.y; v[6]=b.z; v[7]=b.w;
        } else {
            #pragma unroll
            for (int i = 0; i < 8; ++i) v[i] = 0.f;
        }
        half8 h8;
        #pragma unroll
        for (int i = 0; i < 8; ++i) { h8[i] = (_Float16)v[i]; sum += v[i]; }
        *(half8*)(hi + (size_t)row * KPAD + lane * 8) = h8;
    }
    // group 1: g = 64+lane (lanes 0..39; real data for g<98 i.e. lanes 0..33)
    if (lane < 40) {
        int g = 64 + lane;
        float v[8];
        if (row < rows_src && g < 98) {
            float4 a = *(const float4*)(p + g * 8);
            float4 b = *(const float4*)(p + g * 8 + 4);
            v[0]=a.x; v[1]=a.y; v[2]=a.z; v[3]=a.w; v[4]=b.x; v[5]=b.y; v[6]=b.z; v[7]=b.w;
        } else {
            #pragma unroll
            for (int i = 0; i < 8; ++i) v[i] = 0.f;
        }
        half8 h8;
        #pragma unroll
        for (int i = 0; i < 8; ++i) { h8[i] = (_Float16)v[i]; sum += v[i]; }
        *(half8*)(hi + (size_t)row * KPAD + g * 8) = h8;
    }
    #pragma unroll
    for (int off = 32; off > 0; off >>= 1) sum += __shfl_down(sum, off, 64);
    if (lane == 0 && do_sum) strain[row] = sum;
}

// ======== 256x256 8-wave 4-phase/K-tile MFMA GEMM with counted vmcnt ========
// Staging: per K-tile 8 global_load_lds (issue order B0,B1,B2,B3,A0,A1,A2,A3),
// 2 per phase, prefetching tile t+1 while computing tile t (double-buffered).
// Phase p consumes exactly A-inst p (rows p*64..p*64+63) + (p==0) all B.
// Pair-granular waits (tolerate intra-pair issue reorder):
//   main loop: vmcnt 4,6,6,8    tail tile: vmcnt 2,2,0,0

#define G2L(SRCP, LDSP)                                                       \
    __builtin_amdgcn_global_load_lds(                                         \
        (const __attribute__((address_space(1))) void*)(SRCP),                \
        (__attribute__((address_space(3))) void*)(LDSP), 16, 0, 0)

#define STG_A(BUF, C, KT)                                                     \
    G2L(Asrc + soff[C] + (KT),                                                \
        stage + (BUF) * 32768 + ((C) * 512 + wv * 64) * 8)
#define STG_B(BUF, C, KT)                                                     \
    G2L(Bsrc + soff[C] + (KT),                                                \
        stage + (BUF) * 32768 + 16384 + ((C) * 512 + wv * 64) * 8)

#define PH(P, VMN, ...)                                                       \
    {                                                                         \
        __VA_ARGS__;                                                          \
        asm volatile("s_waitcnt vmcnt(" #VMN ")" ::: "memory");               \
        __builtin_amdgcn_sched_barrier(0);                                    \
        __builtin_amdgcn_s_barrier();                                         \
        __builtin_amdgcn_sched_barrier(0);                                    \
        const _Float16* Ab = stage + cur * 32768;                             \
        const _Float16* Bb = Ab + 16384;                                      \
        if ((P) == 0) {                                                       \
            _Pragma("unroll")                                                 \
            for (int j_ = 0; j_ < 4; ++j_) {                                  \
                _Pragma("unroll")                                             \
                for (int k_ = 0; k_ < 2; ++k_) {                              \
                    bfr[j_][k_] = *(const half8*)(Bb + boffs[j_][k_]);        \
                }                                                             \
            }                                                                 \
        }                                                                     \
        half8 afr[2][2];                                                      \
        _Pragma("unroll")                                                     \
        for (int i_ = 0; i_ < 2; ++i_) {                                      \
            _Pragma("unroll")                                                 \
            for (int k_ = 0; k_ < 2; ++k_) {                                  \
                afr[i_][k_] = *(const half8*)(Ab + (P) * 4096 + aoffs[i_][k_]);\
            }                                                                 \
        }                                                                     \
        __builtin_amdgcn_s_setprio(1);                                        \
        _Pragma("unroll")                                                     \
        for (int k_ = 0; k_ < 2; ++k_) {                                      \
            _Pragma("unroll")                                                 \
            for (int i_ = 0; i_ < 2; ++i_) {                                  \
                _Pragma("unroll")                                             \
                for (int j_ = 0; j_ < 4; ++j_) {                              \
                    acc[P][i_][j_] = __builtin_amdgcn_mfma_f32_16x16x32_f16(  \
                        afr[i_][k_], bfr[j_][k_], acc[P][i_][j_], 0, 0, 0);   \
                }                                                             \
            }                                                                 \
        }                                                                     \
        __builtin_amdgcn_s_setprio(0);                                        \
        __builtin_amdgcn_sched_barrier(0);                                    \
        __builtin_amdgcn_s_barrier();                                         \
        __builtin_amdgcn_sched_barrier(0);                                    \
    }

__global__ __launch_bounds__(512, 2)
void knn_mfma(const _Float16* __restrict__ Ah, const _Float16* __restrict__ Bh,
              const float* __restrict__ strain, unsigned* __restrict__ cval) {
    __shared__ char lds_raw[131072] __attribute__((aligned(16)));
    _Float16* stage = (_Float16*)lds_raw;

    // bijective XCD swizzle: each XCD gets a contiguous nchunk band (B-locality)
    const int bid = blockIdx.x;
    const int wgid = (bid & 7) * 196 + (bid >> 3);
    const int mblk = wgid & 7;
    const int nchunk = wgid >> 3;
    const int mb = mblk * 256, nb = nchunk * 256;

    const int tid = threadIdx.x;
    const int wv = tid >> 6, lane = tid & 63;
    const int l15 = lane & 15, q = lane >> 4;
    const int wm = wv & 1, wn = wv >> 1;     // 2M x 4N wave grid

    const _Float16* Asrc = Ah + (size_t)mb * KPAD;
    const _Float16* Bsrc = Bh + (size_t)nb * KPAD;

    // staging source offsets (pre-swizzled global source, linear LDS dest)
    int soff[4];
    #pragma unroll
    for (int c = 0; c < 4; ++c) {
        int cs = c * 512 + tid;              // 16B-chunk index 0..2047
        int rl = cs >> 3;                    // tile-local row 0..255
        int k8 = (cs & 7) ^ (rl & 7);        // swizzled K-chunk
        soff[c] = rl * KPAD + k8 * 8;
    }
    // swizzled ds_read offsets (f16 units); chunk xor depends only on lane
    int aoffs[2][2], boffs[4][2];
    #pragma unroll
    for (int k2 = 0; k2 < 2; ++k2) {
        int ch = (k2 * 4 + q) ^ (l15 & 7);
        #pragma unroll
        for (int i = 0; i < 2; ++i)
            aoffs[i][k2] = ((wm * 32 + i * 16 + l15) * 8 + ch) * 8;
        #pragma unroll
        for (int j = 0; j < 4; ++j)
            boffs[j][k2] = ((wn * 64 + j * 16 + l15) * 8 + ch) * 8;
    }

    float4v acc[4][2][4];
    #pragma unroll
    for (int p = 0; p < 4; ++p)
        #pragma unroll
        for (int i = 0; i < 2; ++i)
            #pragma unroll
            for (int j = 0; j < 4; ++j)
                acc[p][i][j] = (float4v){0.f, 0.f, 0.f, 0.f};
    half8 bfr[4][2];

    // prologue: stage tile 0 into buf0, pinned pair order
    STG_B(0, 0, 0); STG_B(0, 1, 0);
    __builtin_amdgcn_sched_barrier(0);
    STG_B(0, 2, 0); STG_B(0, 3, 0);
    __builtin_amdgcn_sched_barrier(0);
    STG_A(0, 0, 0); STG_A(0, 1, 0);
    __builtin_amdgcn_sched_barrier(0);
    STG_A(0, 2, 0); STG_A(0, 3, 0);

    #pragma unroll 2
    for (int t = 0; t < NT - 1; ++t) {
        const int cur = t & 1;
        const int nxt = cur ^ 1;
        const int ktn = (t + 1) * 64;
        PH(0, 4, STG_B(nxt, 0, ktn); STG_B(nxt, 1, ktn));
        PH(1, 6, STG_B(nxt, 2, ktn); STG_B(nxt, 3, ktn));
        PH(2, 6, STG_A(nxt, 0, ktn); STG_A(nxt, 1, ktn));
        PH(3, 8, STG_A(nxt, 2, ktn); STG_A(nxt, 3, ktn));
    }
    {   // tail tile (t = 12, buf0), no prefetch
        const int cur = 0;
        PH(0, 2, (void)0);
        PH(1, 2, (void)0);
        PH(2, 0, (void)0);
        PH(3, 0, (void)0);
    }

    // ---- epilogue: packed keys + branch-free top-5 per (row, chunk) ----
    float stn[4]; int okn[4];
    #pragma unroll
    for (int j = 0; j < 4; ++j) {
        int n = nb + wn * 64 + j * 16 + l15;
        okn[j] = (n < N_TRAIN);
        stn[j] = okn[j] ? strain[n] : 0.f;
    }
    unsigned* epi = (unsigned*)lds_raw;        // [256 cols][68] u32 (16B aligned)
    unsigned* lvp = epi + 256 * 68;            // [64 rows][41] u32

    #pragma unroll
    for (int p = 0; p < 4; ++p) {              // row-group p = rows p*64..p*64+63
        #pragma unroll
        for (int i = 0; i < 2; ++i) {
            int rloc = wm * 32 + i * 16 + q * 4;
            #pragma unroll
            for (int j = 0; j < 4; ++j) {
                int col = wn * 64 + j * 16 + l15;
                uint4 kv;
                if (okn[j]) {
                    float4v v = acc[p][i][j] * 2.0f;
                    v = v - stn[j];
                    kv.x = pack_key(v.x, col);
                    kv.y = pack_key(v.y, col);
                    kv.z = pack_key(v.z, col);
                    kv.w = pack_key(v.w, col);
                } else {
                    kv.x = kv.y = kv.z = kv.w = (unsigned)col;
                }
                *(uint4*)(epi + col * 68 + rloc) = kv;
            }
        }
        __syncthreads();
        // scan: wave = col-octant, lane = row; branch-free top-5 of 32 cols
        {
            const unsigned* eb = epi + (wv * 32) * 68 + lane;
            unsigned kk[32];
            #pragma unroll
            for (int c = 0; c < 32; ++c) kk[c] = eb[c * 68];
            unsigned m5[TOPK];
            #pragma unroll
            for (int rnd = 0; rnd < TOPK; ++rnd) {
                unsigned t16[16];
                #pragma unroll
                for (int c = 0; c < 16; ++c) t16[c] = umax32(kk[2*c], kk[2*c+1]);
                #pragma unroll
                for (int c = 0; c < 8; ++c) t16[c] = umax32(t16[2*c], t16[2*c+1]);
                #pragma unroll
                for (int c = 0; c < 4; ++c) t16[c] = umax32(t16[2*c], t16[2*c+1]);
                unsigned m = umax32(umax32(t16[0], t16[1]), umax32(t16[2], t16[3]));
                m5[rnd] = m;
                if (rnd < TOPK - 1) {
                    #pragma unroll
                    for (int c = 0; c < 32; ++c) kk[c] = (kk[c] == m) ? 0u : kk[c];
                }
            }
            #pragma unroll
            for (int s = 0; s < TOPK; ++s) lvp[lane * 41 + wv * 5 + s] = m5[s];
        }
        __syncthreads();
        if (tid < 64) {
            unsigned tv[TOPK] = {0u, 0u, 0u, 0u, 0u};
            #pragma unroll
            for (int oc = 0; oc < 8; ++oc)
                #pragma unroll
                for (int s = 0; s < TOPK; ++s) {
                    unsigned cv = lvp[tid * 41 + oc * 5 + s];
                    if (cv > tv[TOPK - 1]) ins5u(tv, cv);
                }
            int grow = mb + p * 64 + tid;
            size_t base = ((size_t)grow * NBLK + nchunk) * TOPK;
            #pragma unroll
            for (int s = 0; s < TOPK; ++s) cval[base + s] = tv[s];
        }
        __syncthreads();
    }
}

// ------- merge packed candidates -> top-8, exact fp64 rescore, vote -------
__global__ __launch_bounds__(256)
void knn_final(const unsigned* __restrict__ cval,
               const float* __restrict__ xt, const float* __restrict__ xtr,
               const int* __restrict__ y, int* __restrict__ out) {
    __shared__ unsigned long long sv[256][SEL];   // 16 KB
    __shared__ double cs[SEL];
    __shared__ int    cn[SEL];
    const int b = blockIdx.x;
    const int t = threadIdx.x;

    unsigned long long tk[SEL];
    #pragma unroll
    for (int s = 0; s < SEL; ++s) tk[s] = 0ull;

    const unsigned* row = cval + (size_t)b * (NBLK * TOPK);
    for (int e = t; e < NBLK * TOPK; e += 256) {
        unsigned v = row[e];
        int chunk = e / TOPK;                       // magic-mul
        unsigned n = (unsigned)chunk * 256u + (v & 255u);
        unsigned long long v64 = ((unsigned long long)v << 16) | n;
        if (v64 > tk[SEL - 1]) ins8(tk, v64);
    }
    #pragma unroll
    for (int s = 0; s < SEL; ++s) sv[t][s] = tk[s];
    __syncthreads();

    for (int off = 128; off >= 1; off >>= 1) {
        if (t < off) {
            if (sv[t + off][0] > tk[SEL - 1]) {
                #pragma unroll
                for (int s = 0; s < SEL; ++s) {
                    unsigned long long v = sv[t + off][s];
                    if (v > tk[SEL - 1]) ins8(tk, v);
                }
                #pragma unroll
                for (int s = 0; s < SEL; ++s) sv[t][s] = tk[s];
            }
        }
        __syncthreads();
    }

    // exact fp64 rescore: candidate c handled by half-wave (w*2 + half)
    const int w = t >> 6, lane = t & 63, half = lane >> 5, hl = lane & 31;
    const int c = w * 2 + half;
    {
        int n = (int)(sv[0][c] & 0xFFFFull);
        double dot = 0.0, rs = 0.0;
        if (n < N_TRAIN) {
            const float4* pa = (const float4*)(xt + (size_t)b * D_DIM);
            const float4* pb = (const float4*)(xtr + (size_t)n * D_DIM);
            #pragma unroll
            for (int jj = 0; jj < 7; ++jj) {
                int j = hl + jj * 32;
                if (j < 196) {
                    float4 a = pa[j], bb = pb[j];
                    dot += (double)a.x * bb.x + (double)a.y * bb.y +
                           (double)a.z * bb.z + (double)a.w * bb.w;
                    rs  += (double)bb.x + (double)bb.y + (double)bb.z + (double)bb.w;
                }
            }
        }
        #pragma unroll
        for (int off = 16; off > 0; off >>= 1) {
            dot += __shfl_down(dot, off, 32);
            rs  += __shfl_down(rs, off, 32);
        }
        if (hl == 0) {
            cs[c] = (n < N_TRAIN) ? (2.0 * dot - rs) : -1.0e300;
            cn[c] = n;
        }
    }
    __syncthreads();

    if (t == 0) {
        double bv[TOPK]; int bi[TOPK];
        #pragma unroll
        for (int s = 0; s < TOPK; ++s) { bv[s] = -1.0e300; bi[s] = 0x7fffffff; }
        for (int cc = 0; cc < SEL; ++cc) {
            double cv = cs[cc]; int ci = cn[cc];
            #pragma unroll
            for (int s = 0; s < TOPK; ++s) {
                bool bet = (cv > bv[s]) || (cv == bv[s] && ci < bi[s]);
                double fv = bet ? bv[s] : cv;
                int    fi = bet ? bi[s] : ci;
                bv[s] = bet ? cv : bv[s];
                bi[s] = bet ? ci : bi[s];
                cv = fv; ci = fi;
            }
        }
        int lab[TOPK];
        #pragma unroll
        for (int s = 0; s < TOPK; ++s) lab[s] = y[bi[s]];
        int best_c = 0, best_cnt = -1;
        #pragma unroll
        for (int cc = 0; cc < N_CLASSES; ++cc) {
            int cnt = 0;
            #pragma unroll
            for (int s = 0; s < TOPK; ++s) cnt += (lab[s] == cc) ? 1 : 0;
            if (cnt > best_cnt) { best_cnt = cnt; best_c = cc; }
        }
        out[b] = best_c;
    }
}

// ================= fallback (round-1 fp32 path, known-correct) =================
#define FBM 64
#define FBN 64
#define FBK 16
#define FNCH 32
#define FCHUNK 1600

__global__ __launch_bounds__(256)
void rowsum_kernel(const float* __restrict__ x, float* __restrict__ s) {
    int row = blockIdx.x * 4 + (threadIdx.x >> 6);
    int lane = threadIdx.x & 63;
    if (row >= N_TRAIN) return;
    const float* p = x + (size_t)row * D_DIM;
    float acc = 0.f;
    for (int i = lane; i < D_DIM; i += 64) acc += p[i];
    #pragma unroll
    for (int off = 32; off > 0; off >>= 1) acc += __shfl_down(acc, off, 64);
    if (lane == 0) s[row] = acc;
}

__global__ __launch_bounds__(256)
void knn_phaseA_fb(const float* __restrict__ xt, const float* __restrict__ xtr,
                   const float* __restrict__ strain,
                   float* __restrict__ cval, int* __restrict__ cidx) {
    __shared__ float As[FBK][FBM + 4];
    __shared__ float Bs[FBK][FBN + 4];
    __shared__ float lv[FBM][16][TOPK];
    __shared__ int   li[FBM][16][TOPK];

    const int tid = threadIdx.x;
    const int tx = tid & 15, ty = tid >> 4;
    const int b0 = blockIdx.x * FBM;
    const int chunk = blockIdx.y;
    const int n_base = chunk * FCHUNK;
    const int lrow = tid >> 2;
    const int lk4  = (tid & 3) * 4;

    float tv[4][TOPK]; int ti[4][TOPK];
    #pragma unroll
    for (int i = 0; i < 4; ++i)
        #pragma unroll
        for (int s = 0; s < TOPK; ++s) { tv[i][s] = -FLT_MAX; ti[i][s] = 0x7fffffff; }

    for (int nt = 0; nt < FCHUNK; nt += FBN) {
        const int n0 = n_base + nt;
        double accd[4][4];
        #pragma unroll
        for (int i = 0; i < 4; ++i)
            #pragma unroll
            for (int j = 0; j < 4; ++j) accd[i][j] = 0.0;

        for (int kt = 0; kt < D_DIM; kt += FBK) {
            float4 av = *(const float4*)(xt + (size_t)(b0 + lrow) * D_DIM + kt + lk4);
            As[lk4 + 0][lrow] = av.x; As[lk4 + 1][lrow] = av.y;
            As[lk4 + 2][lrow] = av.z; As[lk4 + 3][lrow] = av.w;
            int nr = n0 + lrow;
            float4 bv = make_float4(0.f, 0.f, 0.f, 0.f);
            if (nr < N_TRAIN) bv = *(const float4*)(xtr + (size_t)nr * D_DIM + kt + lk4);
            Bs[lk4 + 0][lrow] = bv.x; Bs[lk4 + 1][lrow] = bv.y;
            Bs[lk4 + 2][lrow] = bv.z; Bs[lk4 + 3][lrow] = bv.w;
            __syncthreads();

            float accf[4][4] = {{0.f}};
            #pragma unroll
            for (int k = 0; k < FBK; ++k) {
                float a[4], b[4];
                #pragma unroll
                for (int i = 0; i < 4; ++i) a[i] = As[k][ty * 4 + i];
                #pragma unroll
                for (int j = 0; j < 4; ++j) b[j] = Bs[k][tx * 4 + j];
                #pragma unroll
                for (int i = 0; i < 4; ++i)
                    #pragma unroll
                    for (int j = 0; j < 4; ++j) accf[i][j] += a[i] * b[j];
            }
            #pragma unroll
            for (int i = 0; i < 4; ++i)
                #pragma unroll
                for (int j = 0; j < 4; ++j) accd[i][j] += (double)accf[i][j];
            __syncthreads();
        }

        #pragma unroll
        for (int j = 0; j < 4; ++j) {
            int n = n0 + tx * 4 + j;
            if (n < N_TRAIN) {
                float sn = strain[n];
                #pragma unroll
                for (int i = 0; i < 4; ++i) {
                    float sc = (float)(2.0 * accd[i][j] - (double)sn);
                    if (sc > tv[i][TOPK - 1] ||
                        (sc == tv[i][TOPK - 1] && n < ti[i][TOPK - 1])) {
                        INSERT5(tv[i], ti[i], sc, n);
                    }
                }
            }
        }
    }

    #pragma unroll
    for (int i = 0; i < 4; ++i)
        #pragma unroll
        for (int s = 0; s < TOPK; ++s) {
            lv[ty * 4 + i][tx][s] = tv[i][s];
            li[ty * 4 + i][tx][s] = ti[i][s];
        }
    __syncthreads();

    if (tid < FBM) {
        float bv5[TOPK]; int bi5[TOPK];
        #pragma unroll
        for (int s = 0; s < TOPK; ++s) { bv5[s] = -FLT_MAX; bi5[s] = 0x7fffffff; }
        for (int tt = 0; tt < 16; ++tt)
            #pragma unroll
            for (int s = 0; s < TOPK; ++s) {
                float cv = lv[tid][tt][s]; int ci = li[tid][tt][s];
                if (cv > bv5[TOPK - 1] || (cv == bv5[TOPK - 1] && ci < bi5[TOPK - 1])) {
                    INSERT5(bv5, bi5, cv, ci);
                }
            }
        size_t base = ((size_t)(b0 + tid) * FNCH + chunk) * TOPK;
        #pragma unroll
        for (int s = 0; s < TOPK; ++s) { cval[base + s] = bv5[s]; cidx[base + s] = bi5[s]; }
    }
}

__global__ __launch_bounds__(256)
void knn_phaseB_fb(const float* __restrict__ cval, const int* __restrict__ cidx,
                   const int* __restrict__ y, int* __restrict__ out) {
    int b = blockIdx.x * blockDim.x + threadIdx.x;
    if (b >= B_TEST) return;
    const float* v = cval + (size_t)b * FNCH * TOPK;
    const int* ix = cidx + (size_t)b * FNCH * TOPK;
    float bv5[TOPK]; int bi5[TOPK];
    #pragma unroll
    for (int s = 0; s < TOPK; ++s) { bv5[s] = -FLT_MAX; bi5[s] = 0x7fffffff; }
    for (int tt = 0; tt < FNCH * TOPK; ++tt) {
        float cv = v[tt]; int ci = ix[tt];
        if (cv > bv5[TOPK - 1] || (cv == bv5[TOPK - 1] && ci < bi5[TOPK - 1])) {
            INSERT5(bv5, bi5, cv, ci);
        }
    }
    int lab[TOPK];
    #pragma unroll
    for (int s = 0; s < TOPK; ++s) lab[s] = y[bi5[s]];
    int best_c = 0, best_cnt = -1;
    #pragma unroll
    for (int cc = 0; cc < N_CLASSES; ++cc) {
        int cnt = 0;
        #pragma unroll
        for (int s = 0; s < TOPK; ++s) cnt += (lab[s] == cc) ? 1 : 0;
        if (cnt > best_cnt) { best_cnt = cnt; best_c = cc; }
    }
    out[b] = best_c;
}

// =====================================================================
extern "C" void kernel_launch(void* const* d_in, const int* in_sizes, int n_in,
                              void* d_out, int out_size, void* d_ws, size_t ws_size,
                              hipStream_t stream) {
    const float* x_test  = (const float*)d_in[0];
    const float* x_train = (const float*)d_in[1];
    const int*   y_train = (const int*)d_in[2];
    int* out = (int*)d_out;

    // fast-path workspace layout (bytes)
    const size_t off_Bh = 200704;                          // strain: NPAD floats
    const size_t sz_Bh  = (size_t)NPAD * KPAD * 2;         // 83,492,864
    const size_t off_Ah = off_Bh + sz_Bh;
    const size_t sz_Ah  = (size_t)B_TEST * KPAD * 2;       // 3,407,872
    const size_t off_cv = off_Ah + sz_Ah;
    const size_t sz_cv  = (size_t)B_TEST * NBLK * TOPK * 4;  // 8,028,160
    const size_t need   = off_cv + sz_cv;                  // ~95.1 MB

    char* ws = (char*)d_ws;
    float* strain = (float*)ws;

    if (ws_size >= need) {
        _Float16* Bh = (_Float16*)(ws + off_Bh);
        _Float16* Ah = (_Float16*)(ws + off_Ah);
        unsigned* cval = (unsigned*)(ws + off_cv);

        split_rowsum<<<NPAD / 4, 256, 0, stream>>>(x_train, Bh, strain, N_TRAIN, NPAD, 1);
        split_rowsum<<<B_TEST / 4, 256, 0, stream>>>(x_test, Ah, strain, B_TEST, B_TEST, 0);

        knn_mfma<<<8 * NBLK, 512, 0, stream>>>(Ah, Bh, strain, cval);

        knn_final<<<B_TEST, 256, 0, stream>>>(cval, x_test, x_train, y_train, out);
    } else {
        rowsum_kernel<<<N_TRAIN / 4, 256, 0, stream>>>(x_train, strain);
        float* cval = (float*)(ws + 200192);
        int*   cidx = (int*)(ws + 200192 + (size_t)B_TEST * FNCH * TOPK * 4);

        dim3 gridA(B_TEST / FBM, FNCH);
        knn_phaseA_fb<<<gridA, 256, 0, stream>>>(x_test, x_train, strain, cval, cidx);
        knn_phaseB_fb<<<(B_TEST + 255) / 256, 256, 0, stream>>>(cval, cidx, y_train, out);
    }
}

// Round 2
// 485.063 us; speedup vs baseline: 1.1291x; 1.1291x over previous
//
#include <hip/hip_runtime.h>
#include <float.h>
#include <stdint.h>

#define D_DIM 784
#define KPAD 832            // 13 x 64
#define N_TRAIN 50000
#define NPAD 50048
#define B_TEST 2048
#define N_CLASSES 10
#define TOPK 5
#define NBLK 391            // ceil(50048/128)
#define SEL 8               // exact-rescore candidate count per row

typedef __attribute__((ext_vector_type(8))) _Float16 half8;
typedef __attribute__((ext_vector_type(4))) float float4v;

__device__ inline unsigned umax32(unsigned a, unsigned b) { return a > b ? a : b; }

// monotonic float->u32 key, low 7 bits replaced by col
__device__ inline unsigned pack_key(float s, int col) {
    unsigned u = __float_as_uint(s);
    unsigned mask = (unsigned)((int)u >> 31) | 0x80000000u;
    unsigned k = u ^ mask;
    return (k & 0xFFFFFF80u) | (unsigned)col;
}

// branchless sorted-insert (desc) of u64 into 8-deep list
__device__ inline void ins8(unsigned long long* tk, unsigned long long v) {
    #pragma unroll
    for (int s = 0; s < SEL; ++s) {
        unsigned long long mx = v > tk[s] ? v : tk[s];
        unsigned long long mn = v > tk[s] ? tk[s] : v;
        tk[s] = mx; v = mn;
    }
}

// branchless sorted-insert (desc) of u32 into 5-deep list
__device__ inline void ins5u(unsigned* tk, unsigned v) {
    #pragma unroll
    for (int s = 0; s < TOPK; ++s) {
        unsigned mx = v > tk[s] ? v : tk[s];
        unsigned mn = v > tk[s] ? tk[s] : v;
        tk[s] = mx; v = mn;
    }
}

// float pair-insert for fallback path
#define INSERT5(tvarr, tiarr, CV, CI)                                   \
    {                                                                   \
        float _cv = (CV); int _ci = (CI);                               \
        _Pragma("unroll")                                               \
        for (int _s = 0; _s < TOPK; ++_s) {                             \
            bool _bet = (_cv > tvarr[_s]) ||                            \
                        (_cv == tvarr[_s] && _ci < tiarr[_s]);          \
            float _fv = _bet ? tvarr[_s] : _cv;                         \
            int   _fi = _bet ? tiarr[_s] : _ci;                         \
            tvarr[_s] = _bet ? _cv : tvarr[_s];                         \
            tiarr[_s] = _bet ? _ci : tiarr[_s];                         \
            _cv = _fv; _ci = _fi;                                       \
        }                                                               \
    }

// ------- fused split fp32->f16 + rowsum, BOTH tensors in one launch -------
// blocks [0, NPAD/4): train rows (rowsum -> strain); rest: test rows.
__global__ __launch_bounds__(256)
void split_rowsum2(const float* __restrict__ xtr, const float* __restrict__ xte,
                   _Float16* __restrict__ Bh, _Float16* __restrict__ Ah,
                   float* __restrict__ strain) {
    const int blk = blockIdx.x;
    const float* src;
    _Float16* hi;
    int rows_src, rows_pad, do_sum, row;
    if (blk < NPAD / 4) {
        src = xtr; hi = Bh; rows_src = N_TRAIN; rows_pad = NPAD; do_sum = 1;
        row = blk * 4 + (threadIdx.x >> 6);
    } else {
        src = xte; hi = Ah; rows_src = B_TEST; rows_pad = B_TEST; do_sum = 0;
        row = (blk - NPAD / 4) * 4 + (threadIdx.x >> 6);
    }
    int lane = threadIdx.x & 63;
    if (row >= rows_pad) return;
    const float* p = src + (size_t)row * D_DIM;
    float sum = 0.f;

    // group 0: g = lane (0..63, all real)
    {
        float v[8];
        if (row < rows_src) {
            float4 a = *(const float4*)(p + lane * 8);
            float4 b = *(const float4*)(p + lane * 8 + 4);
            v[0]=a.x; v[1]=a.y; v[2]=a.z; v[3]=a.w; v[4]=b.x; v[5]=b.y; v[6]=b.z; v[7]=b.w;
        } else {
            #pragma unroll
            for (int i = 0; i < 8; ++i) v[i] = 0.f;
        }
        half8 h8;
        #pragma unroll
        for (int i = 0; i < 8; ++i) { h8[i] = (_Float16)v[i]; sum += v[i]; }
        *(half8*)(hi + (size_t)row * KPAD + lane * 8) = h8;
    }
    // group 1: g = 64+lane (lanes 0..39; real data for g<98 i.e. lanes 0..33)
    if (lane < 40) {
        int g = 64 + lane;
        float v[8];
        if (row < rows_src && g < 98) {
            float4 a = *(const float4*)(p + g * 8);
            float4 b = *(const float4*)(p + g * 8 + 4);
            v[0]=a.x; v[1]=a.y; v[2]=a.z; v[3]=a.w; v[4]=b.x; v[5]=b.y; v[6]=b.z; v[7]=b.w;
        } else {
            #pragma unroll
            for (int i = 0; i < 8; ++i) v[i] = 0.f;
        }
        half8 h8;
        #pragma unroll
        for (int i = 0; i < 8; ++i) { h8[i] = (_Float16)v[i]; sum += v[i]; }
        *(half8*)(hi + (size_t)row * KPAD + g * 8) = h8;
    }
    #pragma unroll
    for (int off = 32; off > 0; off >>= 1) sum += __shfl_down(sum, off, 64);
    if (lane == 0 && do_sum) strain[row] = sum;
}

// ---------------- 1-term f16 MFMA GEMM + packed-u32 top-5 epilogue ----------------
// launch_bounds(256,4): 4 blocks/CU (LDS 4x39936=159.7KB fits 160KB; regs 64+64=128
// unified -> 16 waves/CU fits the 2048-reg pool). One extra block of waves to hide
// the per-K-step barrier drain vs round-0's 3 blocks/CU.
__global__ __launch_bounds__(256, 4)
void knn_mfma(const _Float16* __restrict__ Ah, const _Float16* __restrict__ Bh,
              const float* __restrict__ strain, unsigned* __restrict__ cval) {
    const int bid = blockIdx.x;
    const int xcd = bid & 7;
    const int sidx = bid >> 3;
    const int st_g = (sidx >> 4) * 8 + xcd;
    const int r16 = sidx & 15;
    const int mblk = (st_g & 3) * 4 + (r16 & 3);
    const int nchunk = (st_g >> 2) * 4 + (r16 >> 2);
    if (nchunk >= NBLK) return;

    __shared__ char lds_raw[39936] __attribute__((aligned(16)));
    _Float16* stage = (_Float16*)lds_raw;            // 2 tiles x 16 KB
    unsigned* epi  = (unsigned*)lds_raw;             // [128 cols][68] u32
    unsigned* lval = (unsigned*)(lds_raw + 34816);   // [64][4][5] u32

    const int tid = threadIdx.x;
    const int w = tid >> 6, lane = tid & 63;
    const int l15 = lane & 15, q = lane >> 4;
    const int mb = mblk * 128, nb = nchunk * 128;
    const int mw = (w & 1) * 64, nw = (w >> 1) * 64;

    // staging: wave w loads half-tile: tile = w>>1 (0=A,1=B), half = w&1
    const int s_tile = w >> 1, s_half = w & 1;
    const _Float16* sbase = (s_tile == 0) ? (Ah + (size_t)mb * KPAD)
                                          : (Bh + (size_t)nb * KPAD);
    const _Float16* srow = sbase + (size_t)s_half * 64 * KPAD;
    _Float16* ldsw = stage + s_tile * 8192 + s_half * 4096;   // halves

    int choff[8];
    #pragma unroll
    for (int c = 0; c < 8; ++c) {
        int s = c * 64 + lane;
        int rl = s >> 3;
        int k8 = (s & 7) ^ (rl & 7);
        choff[c] = rl * KPAD + k8 * 8;
    }
    int aoff[4][2], boff[4][2];
    #pragma unroll
    for (int i = 0; i < 4; ++i)
        #pragma unroll
        for (int k32 = 0; k32 < 2; ++k32) {
            int r = mw + i * 16 + l15;
            aoff[i][k32] = (r * 8 + ((k32 * 4 + q) ^ (r & 7))) * 8;
            r = nw + i * 16 + l15;
            boff[i][k32] = (r * 8 + ((k32 * 4 + q) ^ (r & 7))) * 8;
        }

    float4v acc[4][4];
    #pragma unroll
    for (int i = 0; i < 4; ++i)
        #pragma unroll
        for (int j = 0; j < 4; ++j)
            acc[i][j] = (float4v){0.f, 0.f, 0.f, 0.f};

    for (int kt = 0; kt < KPAD; kt += 64) {
        #pragma unroll
        for (int c = 0; c < 8; ++c) {
            __builtin_amdgcn_global_load_lds(
                (const __attribute__((address_space(1))) void*)(srow + choff[c] + kt),
                (__attribute__((address_space(3))) void*)(ldsw + c * 512),
                16, 0, 0);
        }
        __syncthreads();
        #pragma unroll
        for (int k32 = 0; k32 < 2; ++k32) {
            half8 a[4], b[4];
            #pragma unroll
            for (int i = 0; i < 4; ++i) a[i] = *(const half8*)(stage + aoff[i][k32]);
            #pragma unroll
            for (int j = 0; j < 4; ++j) b[j] = *(const half8*)(stage + 8192 + boff[j][k32]);
            #pragma unroll
            for (int i = 0; i < 4; ++i)
                #pragma unroll
                for (int j = 0; j < 4; ++j)
                    acc[i][j] = __builtin_amdgcn_mfma_f32_16x16x32_f16(a[i], b[j], acc[i][j], 0, 0, 0);
        }
        __syncthreads();
    }

    // ---- epilogue: packed keys + branch-free top-5 per (row, chunk) ----
    float st[4]; int okn[4];
    #pragma unroll
    for (int j = 0; j < 4; ++j) {
        int n = nb + nw + j * 16 + l15;
        okn[j] = (n < N_TRAIN);
        st[j] = okn[j] ? strain[n] : 0.f;
    }

    for (int h = 0; h < 2; ++h) {
        __syncthreads();
        if ((w & 1) == h) {
            #pragma unroll
            for (int i = 0; i < 4; ++i) {
                int r = i * 16 + q * 4;
                #pragma unroll
                for (int j = 0; j < 4; ++j) {
                    int col = nw + j * 16 + l15;
                    uint4 kv;
                    if (okn[j]) {
                        float4v v = acc[i][j] * 2.0f;
                        v = v - st[j];
                        kv.x = pack_key(v.x, col);
                        kv.y = pack_key(v.y, col);
                        kv.z = pack_key(v.z, col);
                        kv.w = pack_key(v.w, col);
                    } else {
                        kv.x = kv.y = kv.z = kv.w = (unsigned)col;
                    }
                    *(uint4*)(epi + col * 68 + r) = kv;
                }
            }
        }
        __syncthreads();
        // scan: thread t -> row (t&63), col-quarter (t>>6); branch-free extraction
        {
            int r = tid & 63, qq = tid >> 6;
            const unsigned* ebase = epi + (qq * 32) * 68 + r;
            unsigned k[32];
            #pragma unroll
            for (int c = 0; c < 32; ++c) k[c] = ebase[c * 68];
            unsigned m5[TOPK];
            #pragma unroll
            for (int rnd = 0; rnd < TOPK; ++rnd) {
                unsigned t16[16];
                #pragma unroll
                for (int c = 0; c < 16; ++c) t16[c] = umax32(k[2*c], k[2*c+1]);
                #pragma unroll
                for (int c = 0; c < 8; ++c) t16[c] = umax32(t16[2*c], t16[2*c+1]);
                #pragma unroll
                for (int c = 0; c < 4; ++c) t16[c] = umax32(t16[2*c], t16[2*c+1]);
                unsigned m = umax32(umax32(t16[0], t16[1]), umax32(t16[2], t16[3]));
                m5[rnd] = m;
                if (rnd < TOPK - 1) {
                    #pragma unroll
                    for (int c = 0; c < 32; ++c) k[c] = (k[c] == m) ? 0u : k[c];
                }
            }
            #pragma unroll
            for (int s = 0; s < TOPK; ++s) lval[(r * 4 + qq) * TOPK + s] = m5[s];
        }
        __syncthreads();
        if (tid < 64) {
            unsigned tv[TOPK] = {0u, 0u, 0u, 0u, 0u};
            for (int qq = 0; qq < 4; ++qq)
                #pragma unroll
                for (int s = 0; s < TOPK; ++s) {
                    unsigned cv = lval[(tid * 4 + qq) * TOPK + s];
                    if (cv > tv[TOPK - 1]) ins5u(tv, cv);
                }
            int grow = mb + h * 64 + tid;
            size_t base = ((size_t)grow * NBLK + nchunk) * TOPK;
            #pragma unroll
            for (int s = 0; s < TOPK; ++s) cval[base + s] = tv[s];
        }
    }
}

// ------- merge packed candidates -> top-8, exact fp64 rescore, vote -------
__global__ __launch_bounds__(256)
void knn_final(const unsigned* __restrict__ cval,
               const float* __restrict__ xt, const float* __restrict__ xtr,
               const int* __restrict__ y, int* __restrict__ out) {
    __shared__ unsigned long long sv[256][SEL];   // 16 KB
    __shared__ double cs[SEL];
    __shared__ int    cn[SEL];
    const int b = blockIdx.x;
    const int t = threadIdx.x;

    unsigned long long tk[SEL];
    #pragma unroll
    for (int s = 0; s < SEL; ++s) tk[s] = 0ull;

    const unsigned* row = cval + (size_t)b * (NBLK * TOPK);
    for (int e = t; e < NBLK * TOPK; e += 256) {
        unsigned v = row[e];
        int chunk = e / TOPK;                       // magic-mul
        unsigned n = (unsigned)chunk * 128u + (v & 127u);
        unsigned long long v64 = ((unsigned long long)v << 16) | n;
        if (v64 > tk[SEL - 1]) ins8(tk, v64);
    }
    #pragma unroll
    for (int s = 0; s < SEL; ++s) sv[t][s] = tk[s];
    __syncthreads();

    for (int off = 128; off >= 1; off >>= 1) {
        if (t < off) {
            if (sv[t + off][0] > tk[SEL - 1]) {
                #pragma unroll
                for (int s = 0; s < SEL; ++s) {
                    unsigned long long v = sv[t + off][s];
                    if (v > tk[SEL - 1]) ins8(tk, v);
                }
                #pragma unroll
                for (int s = 0; s < SEL; ++s) sv[t][s] = tk[s];
            }
        }
        __syncthreads();
    }

    // exact fp64 rescore: candidate c handled by half-wave (w*2 + half)
    const int w = t >> 6, lane = t & 63, half = lane >> 5, hl = lane & 31;
    const int c = w * 2 + half;
    {
        int n = (int)(sv[0][c] & 0xFFFFull);
        double dot = 0.0, rs = 0.0;
        if (n < N_TRAIN) {
            const float4* pa = (const float4*)(xt + (size_t)b * D_DIM);
            const float4* pb = (const float4*)(xtr + (size_t)n * D_DIM);
            #pragma unroll
            for (int jj = 0; jj < 7; ++jj) {
                int j = hl + jj * 32;
                if (j < 196) {
                    float4 a = pa[j], bb = pb[j];
                    dot += (double)a.x * bb.x + (double)a.y * bb.y +
                           (double)a.z * bb.z + (double)a.w * bb.w;
                    rs  += (double)bb.x + (double)bb.y + (double)bb.z + (double)bb.w;
                }
            }
        }
        #pragma unroll
        for (int off = 16; off > 0; off >>= 1) {
            dot += __shfl_down(dot, off, 32);
            rs  += __shfl_down(rs, off, 32);
        }
        if (hl == 0) {
            cs[c] = (n < N_TRAIN) ? (2.0 * dot - rs) : -1.0e300;
            cn[c] = n;
        }
    }
    __syncthreads();

    if (t == 0) {
        double bv[TOPK]; int bi[TOPK];
        #pragma unroll
        for (int s = 0; s < TOPK; ++s) { bv[s] = -1.0e300; bi[s] = 0x7fffffff; }
        for (int cc = 0; cc < SEL; ++cc) {
            double cv = cs[cc]; int ci = cn[cc];
            #pragma unroll
            for (int s = 0; s < TOPK; ++s) {
                bool bet = (cv > bv[s]) || (cv == bv[s] && ci < bi[s]);
                double fv = bet ? bv[s] : cv;
                int    fi = bet ? bi[s] : ci;
                bv[s] = bet ? cv : bv[s];
                bi[s] = bet ? ci : bi[s];
                cv = fv; ci = fi;
            }
        }
        int lab[TOPK];
        #pragma unroll
        for (int s = 0; s < TOPK; ++s) lab[s] = y[bi[s]];
        int best_c = 0, best_cnt = -1;
        #pragma unroll
        for (int cc = 0; cc < N_CLASSES; ++cc) {
            int cnt = 0;
            #pragma unroll
            for (int s = 0; s < TOPK; ++s) cnt += (lab[s] == cc) ? 1 : 0;
            if (cnt > best_cnt) { best_cnt = cnt; best_c = cc; }
        }
        out[b] = best_c;
    }
}

// ================= fallback (round-1 fp32 path, known-correct) =================
#define FBM 64
#define FBN 64
#define FBK 16
#define FNCH 32
#define FCHUNK 1600

__global__ __launch_bounds__(256)
void rowsum_kernel(const float* __restrict__ x, float* __restrict__ s) {
    int row = blockIdx.x * 4 + (threadIdx.x >> 6);
    int lane = threadIdx.x & 63;
    if (row >= N_TRAIN) return;
    const float* p = x + (size_t)row * D_DIM;
    float acc = 0.f;
    for (int i = lane; i < D_DIM; i += 64) acc += p[i];
    #pragma unroll
    for (int off = 32; off > 0; off >>= 1) acc += __shfl_down(acc, off, 64);
    if (lane == 0) s[row] = acc;
}

__global__ __launch_bounds__(256)
void knn_phaseA_fb(const float* __restrict__ xt, const float* __restrict__ xtr,
                   const float* __restrict__ strain,
                   float* __restrict__ cval, int* __restrict__ cidx) {
    __shared__ float As[FBK][FBM + 4];
    __shared__ float Bs[FBK][FBN + 4];
    __shared__ float lv[FBM][16][TOPK];
    __shared__ int   li[FBM][16][TOPK];

    const int tid = threadIdx.x;
    const int tx = tid & 15, ty = tid >> 4;
    const int b0 = blockIdx.x * FBM;
    const int chunk = blockIdx.y;
    const int n_base = chunk * FCHUNK;
    const int lrow = tid >> 2;
    const int lk4  = (tid & 3) * 4;

    float tv[4][TOPK]; int ti[4][TOPK];
    #pragma unroll
    for (int i = 0; i < 4; ++i)
        #pragma unroll
        for (int s = 0; s < TOPK; ++s) { tv[i][s] = -FLT_MAX; ti[i][s] = 0x7fffffff; }

    for (int nt = 0; nt < FCHUNK; nt += FBN) {
        const int n0 = n_base + nt;
        double accd[4][4];
        #pragma unroll
        for (int i = 0; i < 4; ++i)
            #pragma unroll
            for (int j = 0; j < 4; ++j) accd[i][j] = 0.0;

        for (int kt = 0; kt < D_DIM; kt += FBK) {
            float4 av = *(const float4*)(xt + (size_t)(b0 + lrow) * D_DIM + kt + lk4);
            As[lk4 + 0][lrow] = av.x; As[lk4 + 1][lrow] = av.y;
            As[lk4 + 2][lrow] = av.z; As[lk4 + 3][lrow] = av.w;
            int nr = n0 + lrow;
            float4 bv = make_float4(0.f, 0.f, 0.f, 0.f);
            if (nr < N_TRAIN) bv = *(const float4*)(xtr + (size_t)nr * D_DIM + kt + lk4);
            Bs[lk4 + 0][lrow] = bv.x; Bs[lk4 + 1][lrow] = bv.y;
            Bs[lk4 + 2][lrow] = bv.z; Bs[lk4 + 3][lrow] = bv.w;
            __syncthreads();

            float accf[4][4] = {{0.f}};
            #pragma unroll
            for (int k = 0; k < FBK; ++k) {
                float a[4], b[4];
                #pragma unroll
                for (int i = 0; i < 4; ++i) a[i] = As[k][ty * 4 + i];
                #pragma unroll
                for (int j = 0; j < 4; ++j) b[j] = Bs[k][tx * 4 + j];
                #pragma unroll
                for (int i = 0; i < 4; ++i)
                    #pragma unroll
                    for (int j = 0; j < 4; ++j) accf[i][j] += a[i] * b[j];
            }
            #pragma unroll
            for (int i = 0; i < 4; ++i)
                #pragma unroll
                for (int j = 0; j < 4; ++j) accd[i][j] += (double)accf[i][j];
            __syncthreads();
        }

        #pragma unroll
        for (int j = 0; j < 4; ++j) {
            int n = n0 + tx * 4 + j;
            if (n < N_TRAIN) {
                float sn = strain[n];
                #pragma unroll
                for (int i = 0; i < 4; ++i) {
                    float sc = (float)(2.0 * accd[i][j] - (double)sn);
                    if (sc > tv[i][TOPK - 1] ||
                        (sc == tv[i][TOPK - 1] && n < ti[i][TOPK - 1])) {
                        INSERT5(tv[i], ti[i], sc, n);
                    }
                }
            }
        }
    }

    #pragma unroll
    for (int i = 0; i < 4; ++i)
        #pragma unroll
        for (int s = 0; s < TOPK; ++s) {
            lv[ty * 4 + i][tx][s] = tv[i][s];
            li[ty * 4 + i][tx][s] = ti[i][s];
        }
    __syncthreads();

    if (tid < FBM) {
        float bv5[TOPK]; int bi5[TOPK];
        #pragma unroll
        for (int s = 0; s < TOPK; ++s) { bv5[s] = -FLT_MAX; bi5[s] = 0x7fffffff; }
        for (int tt = 0; tt < 16; ++tt)
            #pragma unroll
            for (int s = 0; s < TOPK; ++s) {
                float cv = lv[tid][tt][s]; int ci = li[tid][tt][s];
                if (cv > bv5[TOPK - 1] || (cv == bv5[TOPK - 1] && ci < bi5[TOPK - 1])) {
                    INSERT5(bv5, bi5, cv, ci);
                }
            }
        size_t base = ((size_t)(b0 + tid) * FNCH + chunk) * TOPK;
        #pragma unroll
        for (int s = 0; s < TOPK; ++s) { cval[base + s] = bv5[s]; cidx[base + s] = bi5[s]; }
    }
}

__global__ __launch_bounds__(256)
void knn_phaseB_fb(const float* __restrict__ cval, const int* __restrict__ cidx,
                   const int* __restrict__ y, int* __restrict__ out) {
    int b = blockIdx.x * blockDim.x + threadIdx.x;
    if (b >= B_TEST) return;
    const float* v = cval + (size_t)b * FNCH * TOPK;
    const int* ix = cidx + (size_t)b * FNCH * TOPK;
    float bv5[TOPK]; int bi5[TOPK];
    #pragma unroll
    for (int s = 0; s < TOPK; ++s) { bv5[s] = -FLT_MAX; bi5[s] = 0x7fffffff; }
    for (int tt = 0; tt < FNCH * TOPK; ++tt) {
        float cv = v[tt]; int ci = ix[tt];
        if (cv > bv5[TOPK - 1] || (cv == bv5[TOPK - 1] && ci < bi5[TOPK - 1])) {
            INSERT5(bv5, bi5, cv, ci);
        }
    }
    int lab[TOPK];
    #pragma unroll
    for (int s = 0; s < TOPK; ++s) lab[s] = y[bi5[s]];
    int best_c = 0, best_cnt = -1;
    #pragma unroll
    for (int cc = 0; cc < N_CLASSES; ++cc) {
        int cnt = 0;
        #pragma unroll
        for (int s = 0; s < TOPK; ++s) cnt += (lab[s] == cc) ? 1 : 0;
        if (cnt > best_cnt) { best_cnt = cnt; best_c = cc; }
    }
    out[b] = best_c;
}

// =====================================================================
extern "C" void kernel_launch(void* const* d_in, const int* in_sizes, int n_in,
                              void* d_out, int out_size, void* d_ws, size_t ws_size,
                              hipStream_t stream) {
    const float* x_test  = (const float*)d_in[0];
    const float* x_train = (const float*)d_in[1];
    const int*   y_train = (const int*)d_in[2];
    int* out = (int*)d_out;

    // fast-path workspace layout (bytes)
    const size_t off_Bh = 200192;                          // strain: NPAD floats
    const size_t sz_Bh  = (size_t)NPAD * KPAD * 2;         // 83,279,872
    const size_t off_Ah = off_Bh + sz_Bh;
    const size_t sz_Ah  = (size_t)B_TEST * KPAD * 2;       // 3,407,872
    const size_t off_cv = off_Ah + sz_Ah;
    const size_t sz_cv  = (size_t)B_TEST * NBLK * TOPK * 4;  // 16,015,360
    const size_t need   = off_cv + sz_cv;                  // ~102.9 MB

    char* ws = (char*)d_ws;
    float* strain = (float*)ws;

    if (ws_size >= need) {
        _Float16* Bh = (_Float16*)(ws + off_Bh);
        _Float16* Ah = (_Float16*)(ws + off_Ah);
        unsigned* cval = (unsigned*)(ws + off_cv);

        split_rowsum2<<<NPAD / 4 + B_TEST / 4, 256, 0, stream>>>(
            x_train, x_test, Bh, Ah, strain);

        knn_mfma<<<6272, 256, 0, stream>>>(Ah, Bh, strain, cval);

        knn_final<<<B_TEST, 256, 0, stream>>>(cval, x_test, x_train, y_train, out);
    } else {
        rowsum_kernel<<<N_TRAIN / 4, 256, 0, stream>>>(x_train, strain);
        float* cval = (float*)(ws + 200192);
        int*   cidx = (int*)(ws + 200192 + (size_t)B_TEST * FNCH * TOPK * 4);

        dim3 gridA(B_TEST / FBM, FNCH);
        knn_phaseA_fb<<<gridA, 256, 0, stream>>>(x_test, x_train, strain, cval, cidx);
        knn_phaseB_fb<<<(B_TEST + 255) / 256, 256, 0, stream>>>(cval, cidx, y_train, out);
    }
}